// Round 17
// baseline (1664.478 us; speedup 1.0000x reference)
//
#include <hip/hip_runtime.h>

#define N_NODES 50000
#define S_NEI 16
#define E_EDGES 400000
#define DDIM 128
#define EDIMC 64
#define NMPC 2
#define DEPTHC 2

typedef __attribute__((ext_vector_type(8))) short short8v;
typedef __attribute__((ext_vector_type(4))) float float4v;

__device__ __forceinline__ unsigned short f2bf(float f) {
  unsigned int u = __float_as_uint(f);
  unsigned int r = (u + 0x7fffu + ((u >> 16) & 1u)) >> 16;
  return (unsigned short)r;
}
__device__ __forceinline__ float bf2f(unsigned short h) { return __uint_as_float((unsigned int)h << 16); }
__device__ __forceinline__ float bfs(short h) { return bf2f((unsigned short)h); }
__device__ __forceinline__ float elu_fast(float x) { return x > 0.f ? x : (__expf(x) - 1.0f); }

// ---------------------------------------------------------------------------
// WT: 27 slots x 16384 bf16. Used slots: ml*6+{0:k_e,1:v_e,3:q_e},
// 24: Wprep^T, 25/26: Wedgeprep^T.
// ---------------------------------------------------------------------------
__global__ void build_wt(const float* __restrict__ Wprep, const float* __restrict__ Wedgeprep,
                         const float* __restrict__ Wq_e, const float* __restrict__ Wk_e,
                         const float* __restrict__ Wv_e, const float* __restrict__ Wq_n,
                         const float* __restrict__ Wk_n, const float* __restrict__ Wv_n,
                         unsigned short* __restrict__ WT) {
  int idx = blockIdx.x * 256 + threadIdx.x;
  if (idx >= 27 * 16384) return;
  int slot = idx >> 14, r = idx & 16383;
  float v = 0.f;
  if (slot < 24) {
    int ml = slot / 6, mat = slot % 6;
    int c = r >> 7, d = r & 127;
    int h = c >> 5, kk = c & 31;
    const float* W = (mat == 0) ? Wk_e : (mat == 1) ? Wv_e : (mat == 2) ? Wq_n
                   : (mat == 3) ? Wq_e : (mat == 4) ? Wk_n : Wv_n;
    v = W[(((size_t)ml * 4 + h) * 128 + d) * 32 + kk];
  } else if (slot == 24) {
    int c = r >> 7, d = r & 127;
    v = Wprep[d * 128 + c];
  } else {
    int mp = slot - 25;
    int c = r >> 6, k = r & 63;
    if (c < 128) v = Wedgeprep[((size_t)mp * 64 + k) * 128 + c];
  }
  WT[idx] = f2bf(v);
}

// QT[(ml*4+h)][c'*128+d] = sum_k Wq_n[ml][h][d][k] * Wk_n[ml][h][c'][k]
__global__ void build_qk(const float* __restrict__ Wq_n, const float* __restrict__ Wk_n,
                         unsigned short* __restrict__ QT) {
  int idx = blockIdx.x * 256 + threadIdx.x;   // 16*16384 total
  int mh = idx >> 14, r = idx & 16383;
  int cp = r >> 7, d = r & 127;
  const float* q = Wq_n + ((size_t)mh * 128 + d) * 32;
  const float* k = Wk_n + ((size_t)mh * 128 + cp) * 32;
  float s = 0.f;
  #pragma unroll
  for (int j = 0; j < 32; ++j) s += q[j] * k[j];
  QT[idx] = f2bf(s);
}

// WV[ml][r=h*32+k'][d] = Wv_n[ml][h][d][k']
__global__ void build_wv(const float* __restrict__ Wv_n, unsigned short* __restrict__ WV) {
  int idx = blockIdx.x * 256 + threadIdx.x;   // 4*16384 total
  int ml = idx >> 14, r14 = idx & 16383;
  int r = r14 >> 7, d = r14 & 127;
  int h = r >> 5, kp = r & 31;
  WV[idx] = f2bf(Wv_n[(((size_t)ml * 4 + h) * 128 + d) * 32 + kp]);
}

// CT[ml][6 slots]: {k_e, v_e, qk_h0..qk_h3} contiguous, for the merged proj.
__global__ void build_ct(const unsigned short* __restrict__ WT, const unsigned short* __restrict__ QT,
                         unsigned short* __restrict__ CT) {
  int idx = blockIdx.x * 256 + threadIdx.x;   // 4*6*16384 total
  int ml = idx / (6 * 16384), r6 = idx % (6 * 16384);
  int slot = r6 >> 14, r = r6 & 16383;
  CT[idx] = (slot < 2) ? WT[((size_t)ml * 6 + slot) * 16384 + r]
                       : QT[((size_t)ml * 4 + (slot - 2)) * 16384 + r];
}

// ---------------------------------------------------------------------------
// proj: Y_w[m][c] = bf16( X[m][:] @ W_w ), up to 6 outputs, row stride rs_w.
// ---------------------------------------------------------------------------
template<int KDIM, int NW, bool ASPLIT>
__global__ __launch_bounds__(256, 3)
void proj(const unsigned short* __restrict__ Xbf, const float* __restrict__ Xf,
          const unsigned short* __restrict__ WT,
          unsigned short* __restrict__ Y0, unsigned short* __restrict__ Y1,
          unsigned short* __restrict__ Y2, unsigned short* __restrict__ Y3,
          unsigned short* __restrict__ Y4, unsigned short* __restrict__ Y5,
          int rs0, int rs1, int rs2, int rs3, int rs4, int rs5, int M) {
  constexpr int NKK  = KDIM / 32;
  constexpr int CHPR = KDIM / 8;
  constexpr int SWZ  = CHPR - 1;
  __shared__ unsigned short Wl[128 * KDIM];
  const int tid  = threadIdx.x;
  const int lane = tid & 63;
  const int wv   = tid >> 6;
  const int l15  = lane & 15, lg = lane >> 4;
  const long m0  = (long)blockIdx.x * 128 + wv * 32;

  short8v xb[2][NKK];
  #pragma unroll
  for (int rf = 0; rf < 2; ++rf) {
    long row = m0 + rf * 16 + l15; if (row >= M) row = M - 1;
    #pragma unroll
    for (int kk = 0; kk < NKK; ++kk) {
      const int k0 = kk * 32 + lg * 8;
      if (ASPLIT) {
        const float* p = Xf + row * KDIM + k0;
        float4v a0 = *(const float4v*)p;
        float4v a1 = *(const float4v*)(p + 4);
        #pragma unroll
        for (int j = 0; j < 8; ++j) {
          float x = (j < 4) ? a0[j] : a1[j - 4];
          xb[rf][kk][j] = (short)f2bf(x);
        }
      } else {
        xb[rf][kk] = *(const short8v*)(Xbf + row * KDIM + k0);
      }
    }
  }

  unsigned short* Ys[6] = {Y0, Y1, Y2, Y3, Y4, Y5};
  const int rsv[6] = {rs0, rs1, rs2, rs3, rs4, rs5};
  #pragma unroll
  for (int w = 0; w < NW; ++w) {
    if (w) __syncthreads();
    {
      const uint4* src = (const uint4*)(WT + (size_t)w * 16384);
      #pragma unroll
      for (int i = 0; i < CHPR / 2; ++i) {
        int ci = i * 256 + tid;
        int row = ci / CHPR, ch = ci & SWZ;
        uint4 v = src[ci];
        *(uint4*)((char*)Wl + row * (KDIM * 2) + ((ch ^ (row & SWZ)) << 4)) = v;
      }
    }
    __syncthreads();

    float4v acc[8][2];
    #pragma unroll
    for (int cf = 0; cf < 8; ++cf)
      #pragma unroll
      for (int rf = 0; rf < 2; ++rf) acc[cf][rf] = (float4v)0.f;

    #pragma unroll
    for (int kk = 0; kk < NKK; ++kk) {
      #pragma unroll
      for (int cf = 0; cf < 8; ++cf) {
        const int row = cf * 16 + l15;
        const int ch  = (kk * 4 + lg) ^ (row & SWZ);
        short8v b = *(const short8v*)((char*)Wl + row * (KDIM * 2) + (ch << 4));
        acc[cf][0] = __builtin_amdgcn_mfma_f32_16x16x32_bf16(b, xb[0][kk], acc[cf][0], 0, 0, 0);
        acc[cf][1] = __builtin_amdgcn_mfma_f32_16x16x32_bf16(b, xb[1][kk], acc[cf][1], 0, 0, 0);
      }
    }

    #pragma unroll
    for (int rf = 0; rf < 2; ++rf) {
      const long m = m0 + rf * 16 + l15;
      if (m < M) {
        #pragma unroll
        for (int cf = 0; cf < 8; ++cf) {
          const int c0 = cf * 16 + lg * 4;
          float4v a = acc[cf][rf];
          ushort4 o;
          o.x = f2bf(a[0]); o.y = f2bf(a[1]); o.z = f2bf(a[2]); o.w = f2bf(a[3]);
          *(ushort4*)(Ys[w] + m * (long)rsv[w] + c0) = o;
        }
      }
    }
  }
}

// ---------------------------------------------------------------------------
// node_attn device body (composed-QK): wave handles node n.
// ---------------------------------------------------------------------------
__device__ __forceinline__
void node_attn_body(long n, int lane,
                    const unsigned short* __restrict__ qt,
                    const unsigned short* __restrict__ eold,
                    const int* __restrict__ n2e, unsigned short* __restrict__ Z) {
  const short8v qv = *(const short8v*)(qt + n * 512 + lane * 8);
  const int i8 = (lane & 15) * 8;
  short8v xk[16];
  #pragma unroll
  for (int s = 0; s < 16; ++s) {
    const long e = n2e[n * 16 + s];
    xk[s] = *(const short8v*)(eold + e * 128 + i8);
  }
  float sc[16];
  #pragma unroll
  for (int s = 0; s < 16; ++s) {
    float p = 0.f;
    #pragma unroll
    for (int j = 0; j < 8; ++j) p += bfs(qv[j]) * bfs(xk[s][j]);
    p += __shfl_xor(p, 1); p += __shfl_xor(p, 2);
    p += __shfl_xor(p, 4); p += __shfl_xor(p, 8);
    sc[s] = p * 0.17677669529663687f;
  }
  float m = sc[0];
  #pragma unroll
  for (int s = 1; s < 16; ++s) m = fmaxf(m, sc[s]);
  float sum = 0.f;
  #pragma unroll
  for (int s = 0; s < 16; ++s) { sc[s] = __expf(sc[s] - m); sum += sc[s]; }
  const float inv = 1.0f / sum;
  float z[8] = {0.f, 0.f, 0.f, 0.f, 0.f, 0.f, 0.f, 0.f};
  #pragma unroll
  for (int s = 0; s < 16; ++s)
    #pragma unroll
    for (int j = 0; j < 8; ++j) z[j] += sc[s] * bfs(xk[s][j]);
  ushort4 o0, o1;
  o0.x = f2bf(z[0] * inv); o0.y = f2bf(z[1] * inv); o0.z = f2bf(z[2] * inv); o0.w = f2bf(z[3] * inv);
  o1.x = f2bf(z[4] * inv); o1.y = f2bf(z[5] * inv); o1.z = f2bf(z[6] * inv); o1.w = f2bf(z[7] * inv);
  *(ushort4*)(Z + n * 512 + lane * 8) = o0;
  *(ushort4*)(Z + n * 512 + lane * 8 + 4) = o1;
}

__global__ __launch_bounds__(256, 2)
void node_attn(const unsigned short* __restrict__ qt, const unsigned short* __restrict__ eold,
               const int* __restrict__ n2e, unsigned short* __restrict__ Z) {
  node_attn_body((long)blockIdx.x * 4 + (threadIdx.x >> 6), threadIdx.x & 63, qt, eold, n2e, Z);
}

// ---------------------------------------------------------------------------
// edge role device body (non-PREP): 8 waves, 16 edge rows per wave, ebid = edge
// block index. K/V gathers at entry; Q-MFMA; attention; LDS-coalesced enew.
// ---------------------------------------------------------------------------
__device__ __forceinline__
void edge_body(int ebid, int tid, unsigned short* Wl,
               const unsigned short* __restrict__ eold, const unsigned short* __restrict__ WTq,
               const unsigned short* __restrict__ KVn, const int* __restrict__ adj,
               unsigned short* __restrict__ enew) {
  const int lane = tid & 63;
  const int wv   = tid >> 6;
  const int l15  = lane & 15, lg = lane >> 4;
  const long m0  = (long)ebid * 128 + wv * 16;
  const long e = m0 + l15;
  const int2 nn = *(const int2*)(adj + e * 2);
  const size_t b0 = (size_t)nn.x * 256, b1 = (size_t)nn.y * 256;

  ushort4 gk0[8], gk1[8], gv0[8], gv1[8];
  #pragma unroll
  for (int cf = 0; cf < 8; ++cf) {
    const int c0 = cf * 16 + lg * 4;
    gk0[cf] = *(const ushort4*)(KVn + b0 + c0);
    gk1[cf] = *(const ushort4*)(KVn + b1 + c0);
    gv0[cf] = *(const ushort4*)(KVn + b0 + 128 + c0);
    gv1[cf] = *(const ushort4*)(KVn + b1 + 128 + c0);
  }

  short8v xb[4];
  {
    const long row = m0 + l15;
    #pragma unroll
    for (int kk = 0; kk < 4; ++kk)
      xb[kk] = *(const short8v*)(eold + row * 128 + kk * 32 + lg * 8);
  }

  {
    const uint4* src = (const uint4*)WTq;
    #pragma unroll
    for (int i = 0; i < 4; ++i) {
      int ci = i * 512 + tid;
      int row = ci >> 4, ch = ci & 15;
      uint4 v = src[ci];
      *(uint4*)((char*)Wl + row * 256 + ((ch ^ (row & 15)) << 4)) = v;
    }
  }
  __syncthreads();

  float4v accQ[8];
  #pragma unroll
  for (int cf = 0; cf < 8; ++cf) accQ[cf] = (float4v)0.f;
  #pragma unroll
  for (int kk = 0; kk < 4; ++kk) {
    #pragma unroll
    for (int cf = 0; cf < 8; ++cf) {
      const int row = cf * 16 + l15;
      const int ch  = (kk * 4 + lg) ^ (row & 15);
      short8v b = *(const short8v*)((char*)Wl + row * 256 + (ch << 4));
      accQ[cf] = __builtin_amdgcn_mfma_f32_16x16x32_bf16(b, xb[kk], accQ[cf], 0, 0, 0);
    }
  }

  const float scale = 0.17677669529663687f;
  ushort4 ov[8];
  {
    float p0[4] = {0.f, 0.f, 0.f, 0.f}, p1[4] = {0.f, 0.f, 0.f, 0.f};
    #pragma unroll
    for (int cf = 0; cf < 8; ++cf) {
      const int h = cf >> 1;
      ushort4 k0 = gk0[cf];
      ushort4 k1 = gk1[cf];
      float4v q = accQ[cf];
      p0[h] += q[0] * bf2f(k0.x) + q[1] * bf2f(k0.y) + q[2] * bf2f(k0.z) + q[3] * bf2f(k0.w);
      p1[h] += q[0] * bf2f(k1.x) + q[1] * bf2f(k1.y) + q[2] * bf2f(k1.z) + q[3] * bf2f(k1.w);
    }
    float a0[4], a1[4];
    #pragma unroll
    for (int h = 0; h < 4; ++h) {
      p0[h] += __shfl_xor(p0[h], 16); p0[h] += __shfl_xor(p0[h], 32);
      p1[h] += __shfl_xor(p1[h], 16); p1[h] += __shfl_xor(p1[h], 32);
      const float s0 = p0[h] * scale, s1 = p1[h] * scale;
      const float mx = fmaxf(s0, s1);
      const float e0 = __expf(s0 - mx), e1 = __expf(s1 - mx);
      const float inv = 1.0f / (e0 + e1);
      a0[h] = e0 * inv; a1[h] = e1 * inv;
    }
    #pragma unroll
    for (int cf = 0; cf < 8; ++cf) {
      const int h = cf >> 1;
      ushort4 v0 = gv0[cf];
      ushort4 v1 = gv1[cf];
      float o[4];
      o[0] = elu_fast(a0[h] * bf2f(v0.x) + a1[h] * bf2f(v1.x));
      o[1] = elu_fast(a0[h] * bf2f(v0.y) + a1[h] * bf2f(v1.y));
      o[2] = elu_fast(a0[h] * bf2f(v0.z) + a1[h] * bf2f(v1.z));
      o[3] = elu_fast(a0[h] * bf2f(v0.w) + a1[h] * bf2f(v1.w));
      ov[cf].x = f2bf(o[0]); ov[cf].y = f2bf(o[1]);
      ov[cf].z = f2bf(o[2]); ov[cf].w = f2bf(o[3]);
    }
  }

  __syncthreads();
  {
    const int er = wv * 16 + l15;
    #pragma unroll
    for (int cf = 0; cf < 8; ++cf) {
      const int ch16 = cf * 2 + (lg >> 1);
      const int off  = er * 256 + ((ch16 ^ (er & 15)) << 4) + (lg & 1) * 8;
      *(ushort4*)((char*)Wl + off) = ov[cf];
    }
  }
  __syncthreads();
  {
    unsigned short* dst = enew + (size_t)ebid * 16384;
    #pragma unroll
    for (int i = 0; i < 4; ++i) {
      int c = i * 512 + tid;
      int row = c >> 4, ch = c & 15;
      uint4 v = *(const uint4*)((char*)Wl + row * 256 + ((ch ^ (row & 15)) << 4));
      *(uint4*)(dst + (size_t)c * 8) = v;
    }
  }
}

// ---------------------------------------------------------------------------
// edge_node: merged independent kernels for l>=1 layers.
//  blocks [0, gE): edge update (edge_body). blocks [gE, gE+6250): node_attn,
//  8 nodes per 512-thread block. The two roles share only read-only inputs.
// ---------------------------------------------------------------------------
__global__ __launch_bounds__(512, 4)
void edge_node(const unsigned short* __restrict__ eold, const unsigned short* __restrict__ WTq,
               const unsigned short* __restrict__ KVn, const int* __restrict__ adj,
               unsigned short* __restrict__ enew,
               const unsigned short* __restrict__ qt, const int* __restrict__ n2e,
               unsigned short* __restrict__ Z, int gE) {
  __shared__ unsigned short Wl[128 * 128];
  const int bid = blockIdx.x;
  if (bid < gE) {
    edge_body(bid, threadIdx.x, Wl, eold, WTq, KVn, adj, enew);
  } else {
    const long n = (long)(bid - gE) * 8 + (threadIdx.x >> 6);
    node_attn_body(n, threadIdx.x & 63, qt, eold, n2e, Z);
  }
}

// ---------------------------------------------------------------------------
// edge_fused<PREP=1>: standalone PREP edge kernel (layer 0) — unchanged r16.
// ---------------------------------------------------------------------------
__global__ __launch_bounds__(512, 4)
void edge_fused_prep(unsigned short* __restrict__ eold, const unsigned short* __restrict__ WTq,
                     const unsigned short* __restrict__ KVn, const int* __restrict__ adj,
                     unsigned short* __restrict__ enew,
                     const float* __restrict__ emb, const unsigned short* __restrict__ WTprep) {
  __shared__ unsigned short Wl[128 * 128];
  const int tid  = threadIdx.x;
  const int lane = tid & 63;
  const int wv   = tid >> 6;
  const int l15  = lane & 15, lg = lane >> 4;
  const long m0  = (long)blockIdx.x * 128 + wv * 16;

  const long e = m0 + l15;
  const int2 nn = *(const int2*)(adj + e * 2);
  const size_t b0 = (size_t)nn.x * 256, b1 = (size_t)nn.y * 256;

  short8v xb[4];
  {
    const uint4* src = (const uint4*)WTprep;
    #pragma unroll
    for (int i = 0; i < 2; ++i) {
      int ci = i * 512 + tid;
      int row = ci >> 3, ch = ci & 7;
      uint4 v = src[ci];
      *(uint4*)((char*)Wl + row * 128 + ((ch ^ (row & 7)) << 4)) = v;
    }
  }
  short8v eb[2];
  {
    const long row = m0 + l15;
    #pragma unroll
    for (int kk = 0; kk < 2; ++kk) {
      const float* p = emb + row * 64 + kk * 32 + lg * 8;
      float4v a0 = *(const float4v*)p;
      float4v a1 = *(const float4v*)(p + 4);
      #pragma unroll
      for (int j = 0; j < 8; ++j) {
        float x = (j < 4) ? a0[j] : a1[j - 4];
        eb[kk][j] = (short)f2bf(x);
      }
    }
  }
  __syncthreads();
  float4v accP[8];
  #pragma unroll
  for (int cf = 0; cf < 8; ++cf) accP[cf] = (float4v)0.f;
  #pragma unroll
  for (int kk = 0; kk < 2; ++kk) {
    #pragma unroll
    for (int cf = 0; cf < 8; ++cf) {
      const int row = cf * 16 + l15;
      const int ch  = (kk * 4 + lg) ^ (row & 7);
      short8v b = *(const short8v*)((char*)Wl + row * 128 + (ch << 4));
      accP[cf] = __builtin_amdgcn_mfma_f32_16x16x32_bf16(b, eb[kk], accP[cf], 0, 0, 0);
    }
  }
  __syncthreads();
  {
    const int er = wv * 16 + l15;
    #pragma unroll
    for (int cf = 0; cf < 8; ++cf) {
      float4v a = accP[cf];
      ushort4 o;
      o.x = f2bf(a[0]); o.y = f2bf(a[1]); o.z = f2bf(a[2]); o.w = f2bf(a[3]);
      const int ch16 = cf * 2 + (lg >> 1);
      const int off  = er * 256 + ((ch16 ^ (er & 15)) << 4) + (lg & 1) * 8;
      *(ushort4*)((char*)Wl + off) = o;
    }
  }
  __syncthreads();
  {
    unsigned short* dst = eold + (size_t)blockIdx.x * 16384;
    #pragma unroll
    for (int i = 0; i < 4; ++i) {
      int c = i * 512 + tid;
      int row = c >> 4, ch = c & 15;
      uint4 v = *(const uint4*)((char*)Wl + row * 256 + ((ch ^ (row & 15)) << 4));
      *(uint4*)(dst + (size_t)c * 8) = v;
    }
  }
  {
    const int row = wv * 16 + l15;
    #pragma unroll
    for (int kk = 0; kk < 4; ++kk) {
      const int ch = (kk * 4 + lg) ^ (row & 15);
      xb[kk] = *(const short8v*)((char*)Wl + row * 256 + (ch << 4));
    }
  }
  __syncthreads();

  {
    const uint4* src = (const uint4*)WTq;
    #pragma unroll
    for (int i = 0; i < 4; ++i) {
      int ci = i * 512 + tid;
      int row = ci >> 4, ch = ci & 15;
      uint4 v = src[ci];
      *(uint4*)((char*)Wl + row * 256 + ((ch ^ (row & 15)) << 4)) = v;
    }
  }
  __syncthreads();

  ushort4 gk0[8], gk1[8], gv0[8], gv1[8];
  #pragma unroll
  for (int cf = 0; cf < 8; ++cf) {
    const int c0 = cf * 16 + lg * 4;
    gk0[cf] = *(const ushort4*)(KVn + b0 + c0);
    gk1[cf] = *(const ushort4*)(KVn + b1 + c0);
    gv0[cf] = *(const ushort4*)(KVn + b0 + 128 + c0);
    gv1[cf] = *(const ushort4*)(KVn + b1 + 128 + c0);
  }

  float4v accQ[8];
  #pragma unroll
  for (int cf = 0; cf < 8; ++cf) accQ[cf] = (float4v)0.f;
  #pragma unroll
  for (int kk = 0; kk < 4; ++kk) {
    #pragma unroll
    for (int cf = 0; cf < 8; ++cf) {
      const int row = cf * 16 + l15;
      const int ch  = (kk * 4 + lg) ^ (row & 15);
      short8v b = *(const short8v*)((char*)Wl + row * 256 + (ch << 4));
      accQ[cf] = __builtin_amdgcn_mfma_f32_16x16x32_bf16(b, xb[kk], accQ[cf], 0, 0, 0);
    }
  }

  const float scale = 0.17677669529663687f;
  ushort4 ov[8];
  {
    float p0[4] = {0.f, 0.f, 0.f, 0.f}, p1[4] = {0.f, 0.f, 0.f, 0.f};
    #pragma unroll
    for (int cf = 0; cf < 8; ++cf) {
      const int h = cf >> 1;
      ushort4 k0 = gk0[cf];
      ushort4 k1 = gk1[cf];
      float4v q = accQ[cf];
      p0[h] += q[0] * bf2f(k0.x) + q[1] * bf2f(k0.y) + q[2] * bf2f(k0.z) + q[3] * bf2f(k0.w);
      p1[h] += q[0] * bf2f(k1.x) + q[1] * bf2f(k1.y) + q[2] * bf2f(k1.z) + q[3] * bf2f(k1.w);
    }
    float a0[4], a1[4];
    #pragma unroll
    for (int h = 0; h < 4; ++h) {
      p0[h] += __shfl_xor(p0[h], 16); p0[h] += __shfl_xor(p0[h], 32);
      p1[h] += __shfl_xor(p1[h], 16); p1[h] += __shfl_xor(p1[h], 32);
      const float s0 = p0[h] * scale, s1 = p1[h] * scale;
      const float mx = fmaxf(s0, s1);
      const float e0 = __expf(s0 - mx), e1 = __expf(s1 - mx);
      const float inv = 1.0f / (e0 + e1);
      a0[h] = e0 * inv; a1[h] = e1 * inv;
    }
    #pragma unroll
    for (int cf = 0; cf < 8; ++cf) {
      const int h = cf >> 1;
      ushort4 v0 = gv0[cf];
      ushort4 v1 = gv1[cf];
      float o[4];
      o[0] = elu_fast(a0[h] * bf2f(v0.x) + a1[h] * bf2f(v1.x));
      o[1] = elu_fast(a0[h] * bf2f(v0.y) + a1[h] * bf2f(v1.y));
      o[2] = elu_fast(a0[h] * bf2f(v0.z) + a1[h] * bf2f(v1.z));
      o[3] = elu_fast(a0[h] * bf2f(v0.w) + a1[h] * bf2f(v1.w));
      ov[cf].x = f2bf(o[0]); ov[cf].y = f2bf(o[1]);
      ov[cf].z = f2bf(o[2]); ov[cf].w = f2bf(o[3]);
    }
  }

  __syncthreads();
  {
    const int er = wv * 16 + l15;
    #pragma unroll
    for (int cf = 0; cf < 8; ++cf) {
      const int ch16 = cf * 2 + (lg >> 1);
      const int off  = er * 256 + ((ch16 ^ (er & 15)) << 4) + (lg & 1) * 8;
      *(ushort4*)((char*)Wl + off) = ov[cf];
    }
  }
  __syncthreads();
  {
    unsigned short* dst = enew + (size_t)blockIdx.x * 16384;
    #pragma unroll
    for (int i = 0; i < 4; ++i) {
      int c = i * 512 + tid;
      int row = c >> 4, ch = c & 15;
      uint4 v = *(const uint4*)((char*)Wl + row * 256 + ((ch ^ (row & 15)) << 4));
      *(uint4*)(dst + (size_t)c * 8) = v;
    }
  }
}

// ---------------------------------------------------------------------------
// node_post: out[n, h*32+k'] = elu( Z[n, h*128..]@Wv_h )
// ---------------------------------------------------------------------------
__global__ __launch_bounds__(256, 2)
void node_post(const unsigned short* __restrict__ Zb, const unsigned short* __restrict__ WV,
               unsigned short* __restrict__ fnext, float* __restrict__ outp, int M) {
  __shared__ unsigned short Wl[128 * 128];
  const int tid  = threadIdx.x;
  const int lane = tid & 63;
  const int wv   = tid >> 6;
  const int l15  = lane & 15, lg = lane >> 4;
  const long m0  = (long)blockIdx.x * 128 + wv * 32;
  {
    const uint4* src = (const uint4*)WV;
    #pragma unroll
    for (int i = 0; i < 8; ++i) {
      int ci = i * 256 + tid;
      int row = ci >> 4, ch = ci & 15;
      uint4 v = src[ci];
      *(uint4*)((char*)Wl + row * 256 + ((ch ^ (row & 15)) << 4)) = v;
    }
  }
  __syncthreads();

  #pragma unroll
  for (int h = 0; h < 4; ++h) {
    float4v acc[2][2];
    #pragma unroll
    for (int cf = 0; cf < 2; ++cf)
      #pragma unroll
      for (int rf = 0; rf < 2; ++rf) acc[cf][rf] = (float4v)0.f;
    #pragma unroll
    for (int rf = 0; rf < 2; ++rf) {
      long row = m0 + rf * 16 + l15; if (row >= M) row = M - 1;
      #pragma unroll
      for (int kk = 0; kk < 4; ++kk) {
        short8v zb = *(const short8v*)(Zb + row * 512 + h * 128 + kk * 32 + lg * 8);
        #pragma unroll
        for (int cf = 0; cf < 2; ++cf) {
          const int arow = h * 32 + cf * 16 + l15;
          const int ch = (kk * 4 + lg) ^ (arow & 15);
          short8v b = *(const short8v*)((char*)Wl + arow * 256 + (ch << 4));
          acc[cf][rf] = __builtin_amdgcn_mfma_f32_16x16x32_bf16(b, zb, acc[cf][rf], 0, 0, 0);
        }
      }
    }
    #pragma unroll
    for (int rf = 0; rf < 2; ++rf) {
      const long m = m0 + rf * 16 + l15;
      if (m < M) {
        #pragma unroll
        for (int cf = 0; cf < 2; ++cf) {
          const int c0 = h * 32 + cf * 16 + lg * 4;
          float o[4];
          #pragma unroll
          for (int j = 0; j < 4; ++j) o[j] = elu_fast(acc[cf][rf][j]);
          ushort4 ob;
          ob.x = f2bf(o[0]); ob.y = f2bf(o[1]); ob.z = f2bf(o[2]); ob.w = f2bf(o[3]);
          *(ushort4*)(fnext + m * 128 + c0) = ob;
          float4 of; of.x = o[0]; of.y = o[1]; of.z = o[2]; of.w = o[3];
          *(float4*)(outp + m * 256 + c0) = of;
        }
      }
    }
  }
}

extern "C" void kernel_launch(void* const* d_in, const int* in_sizes, int n_in,
                              void* d_out, int out_size, void* d_ws, size_t ws_size,
                              hipStream_t stream) {
  const float* feats     = (const float*)d_in[0];
  const float* node_emb  = (const float*)d_in[1];
  const float* Wprep     = (const float*)d_in[2];
  const float* edge_emb  = (const float*)d_in[3];
  const float* Wedgeprep = (const float*)d_in[4];
  const float* Wq_e      = (const float*)d_in[5];
  const float* Wk_e      = (const float*)d_in[6];
  const float* Wv_e      = (const float*)d_in[7];
  const float* Wq_n      = (const float*)d_in[8];
  const float* Wk_n      = (const float*)d_in[9];
  const float* Wv_n      = (const float*)d_in[10];
  const int*   n2e       = (const int*)d_in[11];
  const int*   adj       = (const int*)d_in[12];
  float* out = (float*)d_out;

  char* w = (char*)d_ws;
  auto carve = [&](size_t bytes) -> char* {
    char* p = w; w += (bytes + 255) & ~(size_t)255; return p;
  };
  unsigned short* e_a   = (unsigned short*)carve((size_t)E_EDGES * 128 * 2);
  unsigned short* e_b   = (unsigned short*)carve((size_t)E_EDGES * 128 * 2);
  unsigned short* fprep = (unsigned short*)carve((size_t)N_NODES * 128 * 2);
  unsigned short* fa    = (unsigned short*)carve((size_t)N_NODES * 128 * 2);
  unsigned short* fb    = (unsigned short*)carve((size_t)N_NODES * 128 * 2);
  unsigned short* KVn   = (unsigned short*)carve((size_t)N_NODES * 256 * 2);
  unsigned short* qt    = (unsigned short*)carve((size_t)N_NODES * 512 * 2);
  unsigned short* Zb    = (unsigned short*)carve((size_t)N_NODES * 512 * 2);
  unsigned short* WT    = (unsigned short*)carve((size_t)27 * 16384 * 2);
  unsigned short* QT    = (unsigned short*)carve((size_t)16 * 16384 * 2);
  unsigned short* WV    = (unsigned short*)carve((size_t)4 * 16384 * 2);
  unsigned short* CT    = (unsigned short*)carve((size_t)24 * 16384 * 2);

  build_wt<<<(27 * 16384 + 255) / 256, 256, 0, stream>>>(
      Wprep, Wedgeprep, Wq_e, Wk_e, Wv_e, Wq_n, Wk_n, Wv_n, WT);
  build_qk<<<16 * 64, 256, 0, stream>>>(Wq_n, Wk_n, QT);
  build_wv<<<4 * 64, 256, 0, stream>>>(Wv_n, WV);
  build_ct<<<24 * 64, 256, 0, stream>>>(WT, QT, CT);

  const int gN = (N_NODES + 127) / 128;  // 391
  const int gE = E_EDGES / 128;          // 3125

  proj<128, 1, true><<<gN, 256, 0, stream>>>(
      nullptr, feats, WT + (size_t)24 * 16384, fprep, nullptr, nullptr, nullptr, nullptr, nullptr,
      128, 0, 0, 0, 0, 0, N_NODES);

  for (int mp = 0; mp < NMPC; ++mp) {
    unsigned short *ecur = e_a, *enext = e_b;
    unsigned short *fchi = fprep, *fnhi = fa;
    for (int l = 0; l < DEPTHC; ++l) {
      const int ml = mp * 2 + l;
      const unsigned short* base = WT + (size_t)ml * 6 * 16384;
      const unsigned short* ctb  = CT + (size_t)ml * 6 * 16384;
      const unsigned short* qkb  = QT + (size_t)ml * 4 * 16384;
      if (l == 0) {
        proj<128, 2, false><<<gN, 256, 0, stream>>>(
            fchi, nullptr, ctb, KVn, KVn + 128, nullptr, nullptr, nullptr, nullptr,
            256, 256, 0, 0, 0, 0, N_NODES);
        proj<128, 4, true><<<gN, 256, 0, stream>>>(
            nullptr, node_emb, qkb, qt, qt + 128, qt + 256, qt + 384, nullptr, nullptr,
            512, 512, 512, 512, 0, 0, N_NODES);
        edge_fused_prep<<<gE, 512, 0, stream>>>(
            ecur, base + (size_t)3 * 16384, KVn, adj + (size_t)mp * E_EDGES * 2, enext,
            edge_emb + (size_t)mp * E_EDGES * EDIMC, WT + (size_t)(25 + mp) * 16384);
        node_attn<<<N_NODES / 4, 256, 0, stream>>>(
            qt, ecur, n2e + (size_t)mp * N_NODES * S_NEI, Zb);
      } else {
        // merged proj: KVn (k_e,v_e) + composed qt, one pass over fchi
        proj<128, 6, false><<<gN, 256, 0, stream>>>(
            fchi, nullptr, ctb, KVn, KVn + 128, qt, qt + 128, qt + 256, qt + 384,
            256, 256, 512, 512, 512, 512, N_NODES);
        // merged independent edge-update + node-attention
        edge_node<<<gE + N_NODES / 8, 512, 0, stream>>>(
            ecur, base + (size_t)3 * 16384, KVn, adj + (size_t)mp * E_EDGES * 2, enext,
            qt, n2e + (size_t)mp * N_NODES * S_NEI, Zb, gE);
      }
      node_post<<<gN, 256, 0, stream>>>(
          Zb, WV + (size_t)ml * 16384, fnhi,
          out + (size_t)mp * N_NODES * 256 + (size_t)l * 128, N_NODES);

      unsigned short* t = ecur; ecur = enext; enext = t;
      fchi = fnhi; fnhi = fb;
    }
  }
}

// Round 18
// 1121.212 us; speedup vs baseline: 1.4845x; 1.4845x over previous
//
#include <hip/hip_runtime.h>

#define N_NODES 50000
#define S_NEI 16
#define E_EDGES 400000
#define DDIM 128
#define EDIMC 64
#define NMPC 2
#define DEPTHC 2

typedef __attribute__((ext_vector_type(8))) short short8v;
typedef __attribute__((ext_vector_type(4))) float float4v;

__device__ __forceinline__ unsigned short f2bf(float f) {
  unsigned int u = __float_as_uint(f);
  unsigned int r = (u + 0x7fffu + ((u >> 16) & 1u)) >> 16;
  return (unsigned short)r;
}
__device__ __forceinline__ float bf2f(unsigned short h) { return __uint_as_float((unsigned int)h << 16); }
__device__ __forceinline__ float bfs(short h) { return bf2f((unsigned short)h); }
__device__ __forceinline__ float elu_fast(float x) { return x > 0.f ? x : (__expf(x) - 1.0f); }

// ---------------------------------------------------------------------------
// WT: 27 slots x 16384 bf16. Used slots: ml*6+{0:k_e,1:v_e,3:q_e},
// 24: Wprep^T, 25/26: Wedgeprep^T.
// ---------------------------------------------------------------------------
__global__ void build_wt(const float* __restrict__ Wprep, const float* __restrict__ Wedgeprep,
                         const float* __restrict__ Wq_e, const float* __restrict__ Wk_e,
                         const float* __restrict__ Wv_e, const float* __restrict__ Wq_n,
                         const float* __restrict__ Wk_n, const float* __restrict__ Wv_n,
                         unsigned short* __restrict__ WT) {
  int idx = blockIdx.x * 256 + threadIdx.x;
  if (idx >= 27 * 16384) return;
  int slot = idx >> 14, r = idx & 16383;
  float v = 0.f;
  if (slot < 24) {
    int ml = slot / 6, mat = slot % 6;
    int c = r >> 7, d = r & 127;
    int h = c >> 5, kk = c & 31;
    const float* W = (mat == 0) ? Wk_e : (mat == 1) ? Wv_e : (mat == 2) ? Wq_n
                   : (mat == 3) ? Wq_e : (mat == 4) ? Wk_n : Wv_n;
    v = W[(((size_t)ml * 4 + h) * 128 + d) * 32 + kk];
  } else if (slot == 24) {
    int c = r >> 7, d = r & 127;
    v = Wprep[d * 128 + c];
  } else {
    int mp = slot - 25;
    int c = r >> 6, k = r & 63;
    if (c < 128) v = Wedgeprep[((size_t)mp * 64 + k) * 128 + c];
  }
  WT[idx] = f2bf(v);
}

// QT[(ml*4+h)][c'*128+d] = sum_k Wq_n[ml][h][d][k] * Wk_n[ml][h][c'][k]
__global__ void build_qk(const float* __restrict__ Wq_n, const float* __restrict__ Wk_n,
                         unsigned short* __restrict__ QT) {
  int idx = blockIdx.x * 256 + threadIdx.x;   // 16*16384 total
  int mh = idx >> 14, r = idx & 16383;
  int cp = r >> 7, d = r & 127;
  const float* q = Wq_n + ((size_t)mh * 128 + d) * 32;
  const float* k = Wk_n + ((size_t)mh * 128 + cp) * 32;
  float s = 0.f;
  #pragma unroll
  for (int j = 0; j < 32; ++j) s += q[j] * k[j];
  QT[idx] = f2bf(s);
}

// WV[ml][r=h*32+k'][d] = Wv_n[ml][h][d][k']
__global__ void build_wv(const float* __restrict__ Wv_n, unsigned short* __restrict__ WV) {
  int idx = blockIdx.x * 256 + threadIdx.x;   // 4*16384 total
  int ml = idx >> 14, r14 = idx & 16383;
  int r = r14 >> 7, d = r14 & 127;
  int h = r >> 5, kp = r & 31;
  WV[idx] = f2bf(Wv_n[(((size_t)ml * 4 + h) * 128 + d) * 32 + kp]);
}

// CT[ml][6 slots]: {k_e, v_e, qk_h0..qk_h3} contiguous, for the merged proj.
__global__ void build_ct(const unsigned short* __restrict__ WT, const unsigned short* __restrict__ QT,
                         unsigned short* __restrict__ CT) {
  int idx = blockIdx.x * 256 + threadIdx.x;   // 4*6*16384 total
  int ml = idx / (6 * 16384), r6 = idx % (6 * 16384);
  int slot = r6 >> 14, r = r6 & 16383;
  CT[idx] = (slot < 2) ? WT[((size_t)ml * 6 + slot) * 16384 + r]
                       : QT[((size_t)ml * 4 + (slot - 2)) * 16384 + r];
}

// ---------------------------------------------------------------------------
// proj: Y_w[m][c] = bf16( X[m][:] @ W_w ), up to 6 outputs, row stride rs_w.
// ---------------------------------------------------------------------------
template<int KDIM, int NW, bool ASPLIT>
__global__ __launch_bounds__(256, 3)
void proj(const unsigned short* __restrict__ Xbf, const float* __restrict__ Xf,
          const unsigned short* __restrict__ WT,
          unsigned short* __restrict__ Y0, unsigned short* __restrict__ Y1,
          unsigned short* __restrict__ Y2, unsigned short* __restrict__ Y3,
          unsigned short* __restrict__ Y4, unsigned short* __restrict__ Y5,
          int rs0, int rs1, int rs2, int rs3, int rs4, int rs5, int M) {
  constexpr int NKK  = KDIM / 32;
  constexpr int CHPR = KDIM / 8;
  constexpr int SWZ  = CHPR - 1;
  __shared__ unsigned short Wl[128 * KDIM];
  const int tid  = threadIdx.x;
  const int lane = tid & 63;
  const int wv   = tid >> 6;
  const int l15  = lane & 15, lg = lane >> 4;
  const long m0  = (long)blockIdx.x * 128 + wv * 32;

  short8v xb[2][NKK];
  #pragma unroll
  for (int rf = 0; rf < 2; ++rf) {
    long row = m0 + rf * 16 + l15; if (row >= M) row = M - 1;
    #pragma unroll
    for (int kk = 0; kk < NKK; ++kk) {
      const int k0 = kk * 32 + lg * 8;
      if (ASPLIT) {
        const float* p = Xf + row * KDIM + k0;
        float4v a0 = *(const float4v*)p;
        float4v a1 = *(const float4v*)(p + 4);
        #pragma unroll
        for (int j = 0; j < 8; ++j) {
          float x = (j < 4) ? a0[j] : a1[j - 4];
          xb[rf][kk][j] = (short)f2bf(x);
        }
      } else {
        xb[rf][kk] = *(const short8v*)(Xbf + row * KDIM + k0);
      }
    }
  }

  unsigned short* Ys[6] = {Y0, Y1, Y2, Y3, Y4, Y5};
  const int rsv[6] = {rs0, rs1, rs2, rs3, rs4, rs5};
  #pragma unroll
  for (int w = 0; w < NW; ++w) {
    if (w) __syncthreads();
    {
      const uint4* src = (const uint4*)(WT + (size_t)w * 16384);
      #pragma unroll
      for (int i = 0; i < CHPR / 2; ++i) {
        int ci = i * 256 + tid;
        int row = ci / CHPR, ch = ci & SWZ;
        uint4 v = src[ci];
        *(uint4*)((char*)Wl + row * (KDIM * 2) + ((ch ^ (row & SWZ)) << 4)) = v;
      }
    }
    __syncthreads();

    float4v acc[8][2];
    #pragma unroll
    for (int cf = 0; cf < 8; ++cf)
      #pragma unroll
      for (int rf = 0; rf < 2; ++rf) acc[cf][rf] = (float4v)0.f;

    #pragma unroll
    for (int kk = 0; kk < NKK; ++kk) {
      #pragma unroll
      for (int cf = 0; cf < 8; ++cf) {
        const int row = cf * 16 + l15;
        const int ch  = (kk * 4 + lg) ^ (row & SWZ);
        short8v b = *(const short8v*)((char*)Wl + row * (KDIM * 2) + (ch << 4));
        acc[cf][0] = __builtin_amdgcn_mfma_f32_16x16x32_bf16(b, xb[0][kk], acc[cf][0], 0, 0, 0);
        acc[cf][1] = __builtin_amdgcn_mfma_f32_16x16x32_bf16(b, xb[1][kk], acc[cf][1], 0, 0, 0);
      }
    }

    #pragma unroll
    for (int rf = 0; rf < 2; ++rf) {
      const long m = m0 + rf * 16 + l15;
      if (m < M) {
        #pragma unroll
        for (int cf = 0; cf < 8; ++cf) {
          const int c0 = cf * 16 + lg * 4;
          float4v a = acc[cf][rf];
          ushort4 o;
          o.x = f2bf(a[0]); o.y = f2bf(a[1]); o.z = f2bf(a[2]); o.w = f2bf(a[3]);
          *(ushort4*)(Ys[w] + m * (long)rsv[w] + c0) = o;
        }
      }
    }
  }
}

// ---------------------------------------------------------------------------
// edge_fused<PREP>: 512 threads / 8 waves, 16 edge rows per wave (r16 version).
// ---------------------------------------------------------------------------
template<int PREP>
__global__ __launch_bounds__(512, 4)
void edge_fused(unsigned short* __restrict__ eold, const unsigned short* __restrict__ WTq,
                const unsigned short* __restrict__ KVn, const int* __restrict__ adj,
                unsigned short* __restrict__ enew,
                const float* __restrict__ emb, const unsigned short* __restrict__ WTprep) {
  __shared__ unsigned short Wl[128 * 128];
  const int tid  = threadIdx.x;
  const int lane = tid & 63;
  const int wv   = tid >> 6;
  const int l15  = lane & 15, lg = lane >> 4;
  const long m0  = (long)blockIdx.x * 128 + wv * 16;

  const long e = m0 + l15;
  const int2 nn = *(const int2*)(adj + e * 2);
  const size_t b0 = (size_t)nn.x * 256, b1 = (size_t)nn.y * 256;

  ushort4 gk0[8], gk1[8], gv0[8], gv1[8];
  if (!PREP) {
    #pragma unroll
    for (int cf = 0; cf < 8; ++cf) {
      const int c0 = cf * 16 + lg * 4;
      gk0[cf] = *(const ushort4*)(KVn + b0 + c0);
      gk1[cf] = *(const ushort4*)(KVn + b1 + c0);
      gv0[cf] = *(const ushort4*)(KVn + b0 + 128 + c0);
      gv1[cf] = *(const ushort4*)(KVn + b1 + 128 + c0);
    }
  }

  short8v xb[4];
  if (PREP) {
    {
      const uint4* src = (const uint4*)WTprep;
      #pragma unroll
      for (int i = 0; i < 2; ++i) {
        int ci = i * 512 + tid;
        int row = ci >> 3, ch = ci & 7;
        uint4 v = src[ci];
        *(uint4*)((char*)Wl + row * 128 + ((ch ^ (row & 7)) << 4)) = v;
      }
    }
    short8v eb[2];
    {
      const long row = m0 + l15;
      #pragma unroll
      for (int kk = 0; kk < 2; ++kk) {
        const float* p = emb + row * 64 + kk * 32 + lg * 8;
        float4v a0 = *(const float4v*)p;
        float4v a1 = *(const float4v*)(p + 4);
        #pragma unroll
        for (int j = 0; j < 8; ++j) {
          float x = (j < 4) ? a0[j] : a1[j - 4];
          eb[kk][j] = (short)f2bf(x);
        }
      }
    }
    __syncthreads();
    float4v accP[8];
    #pragma unroll
    for (int cf = 0; cf < 8; ++cf) accP[cf] = (float4v)0.f;
    #pragma unroll
    for (int kk = 0; kk < 2; ++kk) {
      #pragma unroll
      for (int cf = 0; cf < 8; ++cf) {
        const int row = cf * 16 + l15;
        const int ch  = (kk * 4 + lg) ^ (row & 7);
        short8v b = *(const short8v*)((char*)Wl + row * 128 + (ch << 4));
        accP[cf] = __builtin_amdgcn_mfma_f32_16x16x32_bf16(b, eb[kk], accP[cf], 0, 0, 0);
      }
    }
    __syncthreads();
    {
      const int er = wv * 16 + l15;
      #pragma unroll
      for (int cf = 0; cf < 8; ++cf) {
        float4v a = accP[cf];
        ushort4 o;
        o.x = f2bf(a[0]); o.y = f2bf(a[1]); o.z = f2bf(a[2]); o.w = f2bf(a[3]);
        const int ch16 = cf * 2 + (lg >> 1);
        const int off  = er * 256 + ((ch16 ^ (er & 15)) << 4) + (lg & 1) * 8;
        *(ushort4*)((char*)Wl + off) = o;
      }
    }
    __syncthreads();
    {
      unsigned short* dst = eold + (size_t)blockIdx.x * 16384;
      #pragma unroll
      for (int i = 0; i < 4; ++i) {
        int c = i * 512 + tid;
        int row = c >> 4, ch = c & 15;
        uint4 v = *(const uint4*)((char*)Wl + row * 256 + ((ch ^ (row & 15)) << 4));
        *(uint4*)(dst + (size_t)c * 8) = v;
      }
    }
    {
      const int row = wv * 16 + l15;
      #pragma unroll
      for (int kk = 0; kk < 4; ++kk) {
        const int ch = (kk * 4 + lg) ^ (row & 15);
        xb[kk] = *(const short8v*)((char*)Wl + row * 256 + (ch << 4));
      }
    }
    __syncthreads();
  } else {
    const long row = m0 + l15;
    #pragma unroll
    for (int kk = 0; kk < 4; ++kk)
      xb[kk] = *(const short8v*)(eold + row * 128 + kk * 32 + lg * 8);
  }

  {
    const uint4* src = (const uint4*)WTq;
    #pragma unroll
    for (int i = 0; i < 4; ++i) {
      int ci = i * 512 + tid;
      int row = ci >> 4, ch = ci & 15;
      uint4 v = src[ci];
      *(uint4*)((char*)Wl + row * 256 + ((ch ^ (row & 15)) << 4)) = v;
    }
  }
  __syncthreads();

  if (PREP) {
    #pragma unroll
    for (int cf = 0; cf < 8; ++cf) {
      const int c0 = cf * 16 + lg * 4;
      gk0[cf] = *(const ushort4*)(KVn + b0 + c0);
      gk1[cf] = *(const ushort4*)(KVn + b1 + c0);
      gv0[cf] = *(const ushort4*)(KVn + b0 + 128 + c0);
      gv1[cf] = *(const ushort4*)(KVn + b1 + 128 + c0);
    }
  }

  float4v accQ[8];
  #pragma unroll
  for (int cf = 0; cf < 8; ++cf) accQ[cf] = (float4v)0.f;
  #pragma unroll
  for (int kk = 0; kk < 4; ++kk) {
    #pragma unroll
    for (int cf = 0; cf < 8; ++cf) {
      const int row = cf * 16 + l15;
      const int ch  = (kk * 4 + lg) ^ (row & 15);
      short8v b = *(const short8v*)((char*)Wl + row * 256 + (ch << 4));
      accQ[cf] = __builtin_amdgcn_mfma_f32_16x16x32_bf16(b, xb[kk], accQ[cf], 0, 0, 0);
    }
  }

  const float scale = 0.17677669529663687f;
  ushort4 ov[8];
  {
    float p0[4] = {0.f, 0.f, 0.f, 0.f}, p1[4] = {0.f, 0.f, 0.f, 0.f};
    #pragma unroll
    for (int cf = 0; cf < 8; ++cf) {
      const int h = cf >> 1;
      ushort4 k0 = gk0[cf];
      ushort4 k1 = gk1[cf];
      float4v q = accQ[cf];
      p0[h] += q[0] * bf2f(k0.x) + q[1] * bf2f(k0.y) + q[2] * bf2f(k0.z) + q[3] * bf2f(k0.w);
      p1[h] += q[0] * bf2f(k1.x) + q[1] * bf2f(k1.y) + q[2] * bf2f(k1.z) + q[3] * bf2f(k1.w);
    }
    float a0[4], a1[4];
    #pragma unroll
    for (int h = 0; h < 4; ++h) {
      p0[h] += __shfl_xor(p0[h], 16); p0[h] += __shfl_xor(p0[h], 32);
      p1[h] += __shfl_xor(p1[h], 16); p1[h] += __shfl_xor(p1[h], 32);
      const float s0 = p0[h] * scale, s1 = p1[h] * scale;
      const float mx = fmaxf(s0, s1);
      const float e0 = __expf(s0 - mx), e1 = __expf(s1 - mx);
      const float inv = 1.0f / (e0 + e1);
      a0[h] = e0 * inv; a1[h] = e1 * inv;
    }
    #pragma unroll
    for (int cf = 0; cf < 8; ++cf) {
      const int h = cf >> 1;
      ushort4 v0 = gv0[cf];
      ushort4 v1 = gv1[cf];
      float o[4];
      o[0] = elu_fast(a0[h] * bf2f(v0.x) + a1[h] * bf2f(v1.x));
      o[1] = elu_fast(a0[h] * bf2f(v0.y) + a1[h] * bf2f(v1.y));
      o[2] = elu_fast(a0[h] * bf2f(v0.z) + a1[h] * bf2f(v1.z));
      o[3] = elu_fast(a0[h] * bf2f(v0.w) + a1[h] * bf2f(v1.w));
      ov[cf].x = f2bf(o[0]); ov[cf].y = f2bf(o[1]);
      ov[cf].z = f2bf(o[2]); ov[cf].w = f2bf(o[3]);
    }
  }

  __syncthreads();
  {
    const int er = wv * 16 + l15;
    #pragma unroll
    for (int cf = 0; cf < 8; ++cf) {
      const int ch16 = cf * 2 + (lg >> 1);
      const int off  = er * 256 + ((ch16 ^ (er & 15)) << 4) + (lg & 1) * 8;
      *(ushort4*)((char*)Wl + off) = ov[cf];
    }
  }
  __syncthreads();
  {
    unsigned short* dst = enew + (size_t)blockIdx.x * 16384;
    #pragma unroll
    for (int i = 0; i < 4; ++i) {
      int c = i * 512 + tid;
      int row = c >> 4, ch = c & 15;
      uint4 v = *(const uint4*)((char*)Wl + row * 256 + ((ch ^ (row & 15)) << 4));
      *(uint4*)(dst + (size_t)c * 8) = v;
    }
  }
}

// ---------------------------------------------------------------------------
// node_attn (composed-QK): wave per node (r16 version).
// ---------------------------------------------------------------------------
__global__ __launch_bounds__(256, 2)
void node_attn(const unsigned short* __restrict__ qt, const unsigned short* __restrict__ eold,
               const int* __restrict__ n2e, unsigned short* __restrict__ Z) {
  const int lane = threadIdx.x & 63;
  const long n = (long)blockIdx.x * 4 + (threadIdx.x >> 6);
  const short8v qv = *(const short8v*)(qt + n * 512 + lane * 8);
  const int i8 = (lane & 15) * 8;
  short8v xk[16];
  #pragma unroll
  for (int s = 0; s < 16; ++s) {
    const long e = n2e[n * 16 + s];
    xk[s] = *(const short8v*)(eold + e * 128 + i8);
  }
  float sc[16];
  #pragma unroll
  for (int s = 0; s < 16; ++s) {
    float p = 0.f;
    #pragma unroll
    for (int j = 0; j < 8; ++j) p += bfs(qv[j]) * bfs(xk[s][j]);
    p += __shfl_xor(p, 1); p += __shfl_xor(p, 2);
    p += __shfl_xor(p, 4); p += __shfl_xor(p, 8);
    sc[s] = p * 0.17677669529663687f;
  }
  float m = sc[0];
  #pragma unroll
  for (int s = 1; s < 16; ++s) m = fmaxf(m, sc[s]);
  float sum = 0.f;
  #pragma unroll
  for (int s = 0; s < 16; ++s) { sc[s] = __expf(sc[s] - m); sum += sc[s]; }
  const float inv = 1.0f / sum;
  float z[8] = {0.f, 0.f, 0.f, 0.f, 0.f, 0.f, 0.f, 0.f};
  #pragma unroll
  for (int s = 0; s < 16; ++s)
    #pragma unroll
    for (int j = 0; j < 8; ++j) z[j] += sc[s] * bfs(xk[s][j]);
  ushort4 o0, o1;
  o0.x = f2bf(z[0] * inv); o0.y = f2bf(z[1] * inv); o0.z = f2bf(z[2] * inv); o0.w = f2bf(z[3] * inv);
  o1.x = f2bf(z[4] * inv); o1.y = f2bf(z[5] * inv); o1.z = f2bf(z[6] * inv); o1.w = f2bf(z[7] * inv);
  *(ushort4*)(Z + n * 512 + lane * 8) = o0;
  *(ushort4*)(Z + n * 512 + lane * 8 + 4) = o1;
}

// ---------------------------------------------------------------------------
// node_post: out[n, h*32+k'] = elu( Z[n, h*128..]@Wv_h )
// ---------------------------------------------------------------------------
__global__ __launch_bounds__(256, 2)
void node_post(const unsigned short* __restrict__ Zb, const unsigned short* __restrict__ WV,
               unsigned short* __restrict__ fnext, float* __restrict__ outp, int M) {
  __shared__ unsigned short Wl[128 * 128];
  const int tid  = threadIdx.x;
  const int lane = tid & 63;
  const int wv   = tid >> 6;
  const int l15  = lane & 15, lg = lane >> 4;
  const long m0  = (long)blockIdx.x * 128 + wv * 32;
  {
    const uint4* src = (const uint4*)WV;
    #pragma unroll
    for (int i = 0; i < 8; ++i) {
      int ci = i * 256 + tid;
      int row = ci >> 4, ch = ci & 15;
      uint4 v = src[ci];
      *(uint4*)((char*)Wl + row * 256 + ((ch ^ (row & 15)) << 4)) = v;
    }
  }
  __syncthreads();

  #pragma unroll
  for (int h = 0; h < 4; ++h) {
    float4v acc[2][2];
    #pragma unroll
    for (int cf = 0; cf < 2; ++cf)
      #pragma unroll
      for (int rf = 0; rf < 2; ++rf) acc[cf][rf] = (float4v)0.f;
    #pragma unroll
    for (int rf = 0; rf < 2; ++rf) {
      long row = m0 + rf * 16 + l15; if (row >= M) row = M - 1;
      #pragma unroll
      for (int kk = 0; kk < 4; ++kk) {
        short8v zb = *(const short8v*)(Zb + row * 512 + h * 128 + kk * 32 + lg * 8);
        #pragma unroll
        for (int cf = 0; cf < 2; ++cf) {
          const int arow = h * 32 + cf * 16 + l15;
          const int ch = (kk * 4 + lg) ^ (arow & 15);
          short8v b = *(const short8v*)((char*)Wl + arow * 256 + (ch << 4));
          acc[cf][rf] = __builtin_amdgcn_mfma_f32_16x16x32_bf16(b, zb, acc[cf][rf], 0, 0, 0);
        }
      }
    }
    #pragma unroll
    for (int rf = 0; rf < 2; ++rf) {
      const long m = m0 + rf * 16 + l15;
      if (m < M) {
        #pragma unroll
        for (int cf = 0; cf < 2; ++cf) {
          const int c0 = h * 32 + cf * 16 + lg * 4;
          float o[4];
          #pragma unroll
          for (int j = 0; j < 4; ++j) o[j] = elu_fast(acc[cf][rf][j]);
          ushort4 ob;
          ob.x = f2bf(o[0]); ob.y = f2bf(o[1]); ob.z = f2bf(o[2]); ob.w = f2bf(o[3]);
          *(ushort4*)(fnext + m * 128 + c0) = ob;
          float4 of; of.x = o[0]; of.y = o[1]; of.z = o[2]; of.w = o[3];
          *(float4*)(outp + m * 256 + c0) = of;
        }
      }
    }
  }
}

extern "C" void kernel_launch(void* const* d_in, const int* in_sizes, int n_in,
                              void* d_out, int out_size, void* d_ws, size_t ws_size,
                              hipStream_t stream) {
  const float* feats     = (const float*)d_in[0];
  const float* node_emb  = (const float*)d_in[1];
  const float* Wprep     = (const float*)d_in[2];
  const float* edge_emb  = (const float*)d_in[3];
  const float* Wedgeprep = (const float*)d_in[4];
  const float* Wq_e      = (const float*)d_in[5];
  const float* Wk_e      = (const float*)d_in[6];
  const float* Wv_e      = (const float*)d_in[7];
  const float* Wq_n      = (const float*)d_in[8];
  const float* Wk_n      = (const float*)d_in[9];
  const float* Wv_n      = (const float*)d_in[10];
  const int*   n2e       = (const int*)d_in[11];
  const int*   adj       = (const int*)d_in[12];
  float* out = (float*)d_out;

  char* w = (char*)d_ws;
  auto carve = [&](size_t bytes) -> char* {
    char* p = w; w += (bytes + 255) & ~(size_t)255; return p;
  };
  unsigned short* e_a   = (unsigned short*)carve((size_t)E_EDGES * 128 * 2);
  unsigned short* e_b   = (unsigned short*)carve((size_t)E_EDGES * 128 * 2);
  unsigned short* fprep = (unsigned short*)carve((size_t)N_NODES * 128 * 2);
  unsigned short* fa    = (unsigned short*)carve((size_t)N_NODES * 128 * 2);
  unsigned short* fb    = (unsigned short*)carve((size_t)N_NODES * 128 * 2);
  unsigned short* KVn   = (unsigned short*)carve((size_t)N_NODES * 256 * 2);
  unsigned short* qt    = (unsigned short*)carve((size_t)N_NODES * 512 * 2);
  unsigned short* Zb    = (unsigned short*)carve((size_t)N_NODES * 512 * 2);
  unsigned short* WT    = (unsigned short*)carve((size_t)27 * 16384 * 2);
  unsigned short* QT    = (unsigned short*)carve((size_t)16 * 16384 * 2);
  unsigned short* WV    = (unsigned short*)carve((size_t)4 * 16384 * 2);
  unsigned short* CT    = (unsigned short*)carve((size_t)24 * 16384 * 2);

  build_wt<<<(27 * 16384 + 255) / 256, 256, 0, stream>>>(
      Wprep, Wedgeprep, Wq_e, Wk_e, Wv_e, Wq_n, Wk_n, Wv_n, WT);
  build_qk<<<16 * 64, 256, 0, stream>>>(Wq_n, Wk_n, QT);
  build_wv<<<4 * 64, 256, 0, stream>>>(Wv_n, WV);
  build_ct<<<24 * 64, 256, 0, stream>>>(WT, QT, CT);

  const int gN = (N_NODES + 127) / 128;  // 391
  const int gE = E_EDGES / 128;          // 3125

  proj<128, 1, true><<<gN, 256, 0, stream>>>(
      nullptr, feats, WT + (size_t)24 * 16384, fprep, nullptr, nullptr, nullptr, nullptr, nullptr,
      128, 0, 0, 0, 0, 0, N_NODES);

  for (int mp = 0; mp < NMPC; ++mp) {
    unsigned short *ecur = e_a, *enext = e_b;
    unsigned short *fchi = fprep, *fnhi = fa;
    for (int l = 0; l < DEPTHC; ++l) {
      const int ml = mp * 2 + l;
      const unsigned short* base = WT + (size_t)ml * 6 * 16384;
      const unsigned short* ctb  = CT + (size_t)ml * 6 * 16384;
      const unsigned short* qkb  = QT + (size_t)ml * 4 * 16384;
      if (l == 0) {
        proj<128, 2, false><<<gN, 256, 0, stream>>>(
            fchi, nullptr, ctb, KVn, KVn + 128, nullptr, nullptr, nullptr, nullptr,
            256, 256, 0, 0, 0, 0, N_NODES);
        proj<128, 4, true><<<gN, 256, 0, stream>>>(
            nullptr, node_emb, qkb, qt, qt + 128, qt + 256, qt + 384, nullptr, nullptr,
            512, 512, 512, 512, 0, 0, N_NODES);
        edge_fused<1><<<gE, 512, 0, stream>>>(
            ecur, base + (size_t)3 * 16384, KVn, adj + (size_t)mp * E_EDGES * 2, enext,
            edge_emb + (size_t)mp * E_EDGES * EDIMC, WT + (size_t)(25 + mp) * 16384);
      } else {
        // merged proj: KVn (k_e,v_e) + composed qt, one pass over fchi
        proj<128, 6, false><<<gN, 256, 0, stream>>>(
            fchi, nullptr, ctb, KVn, KVn + 128, qt, qt + 128, qt + 256, qt + 384,
            256, 256, 512, 512, 512, 512, N_NODES);
        edge_fused<0><<<gE, 512, 0, stream>>>(
            ecur, base + (size_t)3 * 16384, KVn, adj + (size_t)mp * E_EDGES * 2, enext,
            nullptr, nullptr);
      }
      node_attn<<<N_NODES / 4, 256, 0, stream>>>(
          qt, ecur, n2e + (size_t)mp * N_NODES * S_NEI, Zb);
      node_post<<<gN, 256, 0, stream>>>(
          Zb, WV + (size_t)ml * 16384, fnhi,
          out + (size_t)mp * N_NODES * 256 + (size_t)l * 128, N_NODES);

      unsigned short* t = ecur; ecur = enext; enext = t;
      fchi = fnhi; fnhi = fb;
    }
  }
}